// Round 13
// baseline (506.934 us; speedup 1.0000x reference)
//
#include <hip/hip_runtime.h>

#define NN 50000
#define EE 600000
#define BB 64
#define CH 128
#define LL 3
#define NGB 782   // 64-row tiles: ceil(50000/64) -> ~3 blocks/CU for TLP
#define NSB 196   // scan blocks = ceil(50000/256)
#define NPB 392   // pool blocks = ceil(50000/128)

typedef unsigned short u16;
typedef unsigned int u32;
typedef short s16x8 __attribute__((ext_vector_type(8)));
typedef float f32x4 __attribute__((ext_vector_type(4)));

__device__ __forceinline__ u16 f2b(float f) {
    u32 x = __float_as_uint(f);
    return (u16)((x + 0x7FFFu + ((x >> 16) & 1u)) >> 16);  // RNE f32->bf16
}
__device__ __forceinline__ float b2f(u16 u) {
    return __uint_as_float(((u32)u) << 16);
}

// ---------------------------------------------------------------------------
// zero: deg[NN], pooled[BB*CH], gstats[3*256]
// ---------------------------------------------------------------------------
__global__ __launch_bounds__(256) void k_zero2(int* __restrict__ deg,
                                               float* __restrict__ pooled,
                                               float* __restrict__ gstats) {
    int i = blockIdx.x * 256 + threadIdx.x;
    if (i < NN) deg[i] = 0;
    int j = i - NN;
    if (j >= 0 && j < BB * CH) pooled[j] = 0.f;
    int k = j - BB * CH;
    if (k >= 0 && k < 3 * 256) gstats[k] = 0.f;
}

__global__ __launch_bounds__(256) void k_count(const int* __restrict__ ei,
                                               int* __restrict__ deg) {
    int e = blockIdx.x * 256 + threadIdx.x;
    if (e < EE) atomicAdd(&deg[ei[EE + e]], 1);
}

// stage A: per-block (256 elems) sum of deg -> bsum[blk]
__global__ __launch_bounds__(256) void k_scanA(const int* __restrict__ deg,
                                               int* __restrict__ bsum) {
    __shared__ int sm[256];
    int i = blockIdx.x * 256 + threadIdx.x;
    sm[threadIdx.x] = (i < NN) ? deg[i] : 0;
    __syncthreads();
    for (int off = 128; off > 0; off >>= 1) {
        if (threadIdx.x < off) sm[threadIdx.x] += sm[threadIdx.x + off];
        __syncthreads();
    }
    if (threadIdx.x == 0) bsum[blockIdx.x] = sm[0];
}

// stage B: scan bsum in LDS -> block offset; local scan -> rowptr & cur
__global__ __launch_bounds__(256) void k_scanB(const int* __restrict__ deg,
                                               const int* __restrict__ bsum,
                                               int* __restrict__ rowptr,
                                               int* __restrict__ cur) {
    __shared__ int sb[256], sd[256];
    int t = threadIdx.x;
    sb[t] = (t < NSB) ? bsum[t] : 0;
    __syncthreads();
    for (int off = 1; off < 256; off <<= 1) {
        int v = (t >= off) ? sb[t - off] : 0;
        __syncthreads();
        sb[t] += v;
        __syncthreads();
    }
    int blockOff = (blockIdx.x == 0) ? 0 : sb[blockIdx.x - 1];
    int i = blockIdx.x * 256 + t;
    int d = (i < NN) ? deg[i] : 0;
    sd[t] = d;
    __syncthreads();
    for (int off = 1; off < 256; off <<= 1) {
        int v = (t >= off) ? sd[t - off] : 0;
        __syncthreads();
        sd[t] += v;
        __syncthreads();
    }
    int excl = blockOff + sd[t] - d;
    if (i < NN) { rowptr[i] = excl; cur[i] = excl; }
    if (i == NN - 1) rowptr[NN] = excl + d;
}

__global__ __launch_bounds__(256) void k_fill(const int* __restrict__ ei,
                                              int* __restrict__ cur,
                                              int* __restrict__ perm) {
    int e = blockIdx.x * 256 + threadIdx.x;
    if (e < EE) {
        int dst = ei[EE + e];
        int idx = atomicAdd(&cur[dst], 1);
        perm[idx] = ei[e];
    }
}

// x16 = bf16(x_in), 8 elements/thread. grid 3125 x 256.
__global__ __launch_bounds__(256) void k_cvt(const float* __restrict__ x,
                                             u16* __restrict__ y) {
    long base = (long)(blockIdx.x * 256 + threadIdx.x) * 8;
    if (base < (long)NN * CH) {
        float4 f0 = *(const float4*)(x + base);
        float4 f1 = *(const float4*)(x + base + 4);
        union { u16 pk[8]; uint4 v; } uu;
        uu.pk[0] = f2b(f0.x); uu.pk[1] = f2b(f0.y);
        uu.pk[2] = f2b(f0.z); uu.pk[3] = f2b(f0.w);
        uu.pk[4] = f2b(f1.x); uu.pk[5] = f2b(f1.y);
        uu.pk[6] = f2b(f1.z); uu.pk[7] = f2b(f1.w);
        *(uint4*)(y + base) = uu.v;
    }
}

// ---------------------------------------------------------------------------
// Transpose + convert weights once: Wt[slot][n*128+k] = bf16(W[k][n])
// slots 0-2: convW1[l], 3-5: convW2[l], 6: recW1, 7: recW2, 8: recW3 (zero-pad)
// ---------------------------------------------------------------------------
__global__ __launch_bounds__(256) void k_transpose_all(
    const float* __restrict__ cW1, const float* __restrict__ cW2,
    const float* __restrict__ rW1, const float* __restrict__ rW2,
    const float* __restrict__ rW3, u16* __restrict__ Wt) {
    int idx = blockIdx.x * 256 + threadIdx.x;
    if (idx < 8 * 16384) {
        int slot = idx >> 14;
        int wi = idx & 16383;
        int k = wi >> 7, n = wi & 127;
        const float* src = slot < 3 ? cW1 + slot * 16384
                         : slot < 6 ? cW2 + (slot - 3) * 16384
                         : slot == 6 ? rW1 : rW2;
        Wt[slot * 16384 + n * 128 + k] = f2b(src[wi]);
    } else if (idx < 9 * 16384) {
        int j = idx - 8 * 16384;
        int n = j >> 7, k = j & 127;
        Wt[8 * 16384 + j] = (n < 4) ? f2b(rW3[k * 4 + n]) : (u16)0;
    }
}

// ---------------------------------------------------------------------------
// 64-row GEMM building blocks (layouts verified m89/m91; XOR-swizzle c^(r&15))
// Block = 256 threads = 4 waves; wave wv owns rows wv*16..wv*16+15.
// LDS: sA 64x128 (16 KB) + sB 128x128 (32 KB) = 48 KB -> 3 blocks/CU.
// ---------------------------------------------------------------------------
__device__ __forceinline__ void stageB8(const u16* __restrict__ Wt, u16* sB,
                                        int s, int rr) {
#pragma unroll
    for (int it = 0; it < 8; ++it) {
        int n = it * 16 + rr;
        uint4 u = *(const uint4*)(Wt + n * CH + 8 * s);
        *(uint4*)(&sB[n * CH + ((s ^ (n & 15)) * 8)]) = u;
    }
}

// 8 column-tiles over full K for this wave's 16 rows.
__device__ __forceinline__ void mfma64(const u16* sA, const u16* sB,
                                       f32x4 acc[8], int wv, int quad, int l16) {
    f32x4 z = {0.f, 0.f, 0.f, 0.f};
#pragma unroll
    for (int t = 0; t < 8; ++t) acc[t] = z;
    const u16* pa = sA + (wv * 16 + l16) * CH;
#pragma unroll
    for (int kc = 0; kc < 4; ++kc) {
        int off = (((kc << 2) | quad) ^ l16) << 3;
        s16x8 a0 = *(const s16x8*)(pa + off);
#pragma unroll
        for (int t = 0; t < 8; ++t) {
            s16x8 bfr = *(const s16x8*)(sB + (t * 16 + l16) * CH + off);
            acc[t] = __builtin_amdgcn_mfma_f32_16x16x32_bf16(a0, bfr, acc[t], 0, 0, 0);
        }
    }
}

__device__ __forceinline__ void biasrelu64(f32x4 acc[8],
                                           const float* __restrict__ bias, int l16) {
#pragma unroll
    for (int t = 0; t < 8; ++t) {
        float bv = bias[t * 16 + l16];
#pragma unroll
        for (int r = 0; r < 4; ++r)
            acc[t][r] = fmaxf(acc[t][r] + bv, 0.f);
    }
}

// write C tile (in acc) back into sA as bf16 with the A-read XOR-swizzle.
// C/D: col=t*16+l16, row(local16)=quad*4+r  -> lr = wv*16 + quad*4 + r.
__device__ __forceinline__ void restage64(const f32x4 acc[8], u16* sA,
                                          int wv, int quad, int l16) {
#pragma unroll
    for (int t = 0; t < 8; ++t) {
        int chunk = (t << 1) | (l16 >> 3);
        int o7 = l16 & 7;
#pragma unroll
        for (int r = 0; r < 4; ++r) {
            int lr = wv * 16 + quad * 4 + r;
            sA[lr * CH + ((chunk ^ (lr & 15)) << 3) + o7] = f2b(acc[t][r]);
        }
    }
}

// gather 64 rows of (x[dst] + sum_src x[src]) straight into swizzled sA.
// 16 groups of 16 lanes; group handles 4 rows sequentially; 2-way unroll.
__device__ __forceinline__ void gatherA(const u16* __restrict__ x,
                                        const int* __restrict__ rowptr,
                                        const int* __restrict__ perm,
                                        u16* sA, int r0, int s, int rr) {
#pragma unroll
    for (int j = 0; j < 4; ++j) {
        int lr = rr * 4 + j;
        int gr = r0 + lr;
        union { u16 pk[8]; uint4 v; } uu;
        if (gr < NN) {
            uu.v = *(const uint4*)(x + (long)gr * CH + 8 * s);
            float a[8], b[8];
#pragma unroll
            for (int q = 0; q < 8; ++q) { a[q] = b2f(uu.pk[q]); b[q] = 0.f; }
            int e = rowptr[gr], end = rowptr[gr + 1];
            for (; e + 1 < end; e += 2) {
                int s0 = perm[e], s1 = perm[e + 1];
                union { u16 pk[8]; uint4 v; } v0, v1;
                v0.v = *(const uint4*)(x + (long)s0 * CH + 8 * s);
                v1.v = *(const uint4*)(x + (long)s1 * CH + 8 * s);
#pragma unroll
                for (int q = 0; q < 8; ++q) { a[q] += b2f(v0.pk[q]); b[q] += b2f(v1.pk[q]); }
            }
            if (e < end) {
                int s0 = perm[e];
                union { u16 pk[8]; uint4 v; } v0;
                v0.v = *(const uint4*)(x + (long)s0 * CH + 8 * s);
#pragma unroll
                for (int q = 0; q < 8; ++q) a[q] += b2f(v0.pk[q]);
            }
#pragma unroll
            for (int q = 0; q < 8; ++q) uu.pk[q] = f2b(a[q] + b[q]);
        } else {
#pragma unroll
            for (int q = 0; q < 8; ++q) uu.pk[q] = 0;
        }
        *(uint4*)(&sA[lr * CH + ((s ^ (lr & 15)) * 8)]) = uu.v;
    }
}

// ---------------------------------------------------------------------------
// Fused gather + GEMM1 + stats: h = (x[i]+sum_j x[j]) @ W1 + b1 (pre-relu),
// written bf16; per-block channel sum/sumsq atomically added to gstats[256].
// ---------------------------------------------------------------------------
__global__ __launch_bounds__(256, 3) void k_g1(
    const u16* __restrict__ x, const int* __restrict__ rowptr,
    const int* __restrict__ perm, const u16* __restrict__ Wt1,
    const float* __restrict__ cb1, u16* __restrict__ h16,
    float* __restrict__ gstats) {
    __shared__ u16 sA[64 * CH];    // 16 KB
    __shared__ u16 sB[128 * CH];   // 32 KB
    const int tid = threadIdx.x;
    const int s = tid & 15, rr = tid >> 4;
    const int r0 = blockIdx.x * 64;
    const int lane = tid & 63, wv = tid >> 6, quad = lane >> 4, l16 = lane & 15;

    stageB8(Wt1, sB, s, rr);
    gatherA(x, rowptr, perm, sA, r0, s, rr);
    __syncthreads();

    f32x4 acc[8];
    mfma64(sA, sB, acc, wv, quad, l16);

    // bias add (keep pre-relu h), stats over valid rows, write h16
    float ss[8], qq[8];
#pragma unroll
    for (int t = 0; t < 8; ++t) {
        float bv = cb1[t * 16 + l16];
        int col = t * 16 + l16;
        ss[t] = 0.f; qq[t] = 0.f;
        int rbase = r0 + wv * 16 + quad * 4;
#pragma unroll
        for (int r = 0; r < 4; ++r) {
            float v = acc[t][r] + bv;
            int row = rbase + r;
            if (row < NN) {
                ss[t] += v; qq[t] += v * v;
                h16[(long)row * CH + col] = f2b(v);
            }
        }
    }
#pragma unroll
    for (int t = 0; t < 8; ++t) {
        ss[t] += __shfl_xor(ss[t], 16);
        ss[t] += __shfl_xor(ss[t], 32);
        qq[t] += __shfl_xor(qq[t], 16);
        qq[t] += __shfl_xor(qq[t], 32);
    }
    float* red = (float*)sA;   // sA dead after mfma
    __syncthreads();
    if (lane < 16) {
#pragma unroll
        for (int t = 0; t < 8; ++t) {
            red[wv * 256 + t * 16 + l16] = ss[t];
            red[wv * 256 + 128 + t * 16 + l16] = qq[t];
        }
    }
    __syncthreads();
    unsafeAtomicAdd(&gstats[tid],
                    red[tid] + red[256 + tid] + red[512 + tid] + red[768 + tid]);
}

// BN params from gstats. 1 block x 128.
__global__ __launch_bounds__(128) void k_bnparam(const float* __restrict__ gstats,
                                                 const float* __restrict__ g,
                                                 const float* __restrict__ b,
                                                 float* __restrict__ scale,
                                                 float* __restrict__ shift) {
    int t = threadIdx.x;
    float mu = gstats[t] / (float)NN;
    float var = gstats[128 + t] / (float)NN - mu * mu;
    float rstd = rsqrtf(var + 1e-5f);
    float sc = g[t] * rstd;
    scale[t] = sc;
    shift[t] = b[t] - mu * sc;
}

// ---------------------------------------------------------------------------
// GEMM2 (layers 0,1): xc = relu(relu(BN(h16)) @ W2 + b2), BN fused in staging.
// ---------------------------------------------------------------------------
__global__ __launch_bounds__(256, 3) void k_g2(
    const u16* __restrict__ h16, const u16* __restrict__ Wt2,
    const float* __restrict__ cb2, const float* __restrict__ scale,
    const float* __restrict__ shift, u16* __restrict__ xc) {
    __shared__ u16 sA[64 * CH];
    __shared__ u16 sB[128 * CH];
    const int tid = threadIdx.x;
    const int s = tid & 15, rr = tid >> 4;
    const int r0 = blockIdx.x * 64;
    const int lane = tid & 63, wv = tid >> 6, quad = lane >> 4, l16 = lane & 15;

    float sc[8], sh[8];
#pragma unroll
    for (int j = 0; j < 8; ++j) { sc[j] = scale[8 * s + j]; sh[j] = shift[8 * s + j]; }

    stageB8(Wt2, sB, s, rr);
#pragma unroll
    for (int it = 0; it < 4; ++it) {
        int lr = it * 16 + rr;
        int gr = r0 + lr;
        union { u16 pk[8]; uint4 v; } uu;
        if (gr < NN) {
            uu.v = *(const uint4*)(h16 + (long)gr * CH + 8 * s);
#pragma unroll
            for (int j = 0; j < 8; ++j)
                uu.pk[j] = f2b(fmaxf(b2f(uu.pk[j]) * sc[j] + sh[j], 0.f));
        } else {
#pragma unroll
            for (int j = 0; j < 8; ++j) uu.pk[j] = 0;
        }
        *(uint4*)(&sA[lr * CH + ((s ^ (lr & 15)) * 8)]) = uu.v;
    }
    __syncthreads();

    f32x4 acc[8];
    mfma64(sA, sB, acc, wv, quad, l16);
    biasrelu64(acc, cb2, l16);
#pragma unroll
    for (int t = 0; t < 8; ++t) {
        int col = t * 16 + l16;
        int rbase = r0 + wv * 16 + quad * 4;
#pragma unroll
        for (int r = 0; r < 4; ++r) {
            int row = rbase + r;
            if (row < NN) xc[(long)row * CH + col] = f2b(acc[t][r]);
        }
    }
}

// ---------------------------------------------------------------------------
// Last-layer tail: GEMM2(l=2) + rec1 + rec2 + rec3, tile-resident.
// ---------------------------------------------------------------------------
__global__ __launch_bounds__(256, 3) void k_tail(
    const u16* __restrict__ h16, const u16* __restrict__ Wt,
    const float* __restrict__ cb2, const float* __restrict__ scale,
    const float* __restrict__ shift, const float* __restrict__ rb1,
    const float* __restrict__ rb2, const float* __restrict__ rb3,
    u16* __restrict__ xc, float* __restrict__ x_rec) {
    __shared__ u16 sA[64 * CH];
    __shared__ u16 sB[128 * CH];
    const int tid = threadIdx.x;
    const int s = tid & 15, rr = tid >> 4;
    const int r0 = blockIdx.x * 64;
    const int lane = tid & 63, wv = tid >> 6, quad = lane >> 4, l16 = lane & 15;

    float sc[8], sh[8];
#pragma unroll
    for (int j = 0; j < 8; ++j) { sc[j] = scale[8 * s + j]; sh[j] = shift[8 * s + j]; }

    // ---- GEMM2 (layer 2) ----
    stageB8(Wt + 5 * 16384, sB, s, rr);
#pragma unroll
    for (int it = 0; it < 4; ++it) {
        int lr = it * 16 + rr;
        int gr = r0 + lr;
        union { u16 pk[8]; uint4 v; } uu;
        if (gr < NN) {
            uu.v = *(const uint4*)(h16 + (long)gr * CH + 8 * s);
#pragma unroll
            for (int j = 0; j < 8; ++j)
                uu.pk[j] = f2b(fmaxf(b2f(uu.pk[j]) * sc[j] + sh[j], 0.f));
        } else {
#pragma unroll
            for (int j = 0; j < 8; ++j) uu.pk[j] = 0;
        }
        *(uint4*)(&sA[lr * CH + ((s ^ (lr & 15)) * 8)]) = uu.v;
    }
    __syncthreads();

    f32x4 acc[8];
    mfma64(sA, sB, acc, wv, quad, l16);
    biasrelu64(acc, cb2, l16);
#pragma unroll
    for (int t = 0; t < 8; ++t) {
        int col = t * 16 + l16;
        int rbase = r0 + wv * 16 + quad * 4;
#pragma unroll
        for (int r = 0; r < 4; ++r) {
            int row = rbase + r;
            if (row < NN) xc[(long)row * CH + col] = f2b(acc[t][r]);
        }
    }
    // ---- rec1 ----
    __syncthreads();
    restage64(acc, sA, wv, quad, l16);
    stageB8(Wt + 6 * 16384, sB, s, rr);
    __syncthreads();
    mfma64(sA, sB, acc, wv, quad, l16);
    biasrelu64(acc, rb1, l16);
    // ---- rec2 ----
    __syncthreads();
    restage64(acc, sA, wv, quad, l16);
    stageB8(Wt + 7 * 16384, sB, s, rr);
    __syncthreads();
    mfma64(sA, sB, acc, wv, quad, l16);
    biasrelu64(acc, rb2, l16);
    // ---- rec3 (N=4, single 16-col tile) ----
    __syncthreads();
    restage64(acc, sA, wv, quad, l16);
    {
        int n = rr;  // 16 B-rows
        uint4 u = *(const uint4*)(Wt + 8 * 16384 + n * CH + 8 * s);
        *(uint4*)(&sB[n * CH + ((s ^ (n & 15)) * 8)]) = u;
    }
    __syncthreads();
    f32x4 a4 = {0.f, 0.f, 0.f, 0.f};
    const u16* pa = sA + (wv * 16 + l16) * CH;
#pragma unroll
    for (int kc = 0; kc < 4; ++kc) {
        int off = (((kc << 2) | quad) ^ l16) << 3;
        s16x8 a0 = *(const s16x8*)(pa + off);
        s16x8 bfr = *(const s16x8*)(sB + l16 * CH + off);
        a4 = __builtin_amdgcn_mfma_f32_16x16x32_bf16(a0, bfr, a4, 0, 0, 0);
    }
    if (l16 < 4) {
        float bv = rb3[l16];
        int rbase = r0 + wv * 16 + quad * 4;
#pragma unroll
        for (int r = 0; r < 4; ++r) {
            int row = rbase + r;
            if (row < NN) x_rec[(long)row * 4 + l16] = fmaxf(a4[r] + bv, 0.f);
        }
    }
}

// ---------------------------------------------------------------------------
// global_add_pool, parallel: 392 blocks x 128 rows; run-length accumulate.
// ---------------------------------------------------------------------------
__global__ __launch_bounds__(256) void k_pool(const u16* __restrict__ x,
                                              const int* __restrict__ batch,
                                              float* __restrict__ pooled) {
    int r0 = blockIdx.x * 128;
    if (r0 >= NN) return;
    int rend = r0 + 128 < NN ? r0 + 128 : NN;
    int c = threadIdx.x & 127;
    int half = threadIdx.x >> 7;
    int r = r0 + half;
    if (r >= rend) return;
    int g = batch[r];
    float s = 0.f;
    for (; r < rend; r += 2) {
        int gg = batch[r];
        if (gg != g) {
            unsafeAtomicAdd(pooled + g * CH + c, s);
            s = 0.f;
            g = gg;
        }
        s += b2f(x[(long)r * CH + c]);
    }
    unsafeAtomicAdd(pooled + g * CH + c, s);
}

// out[b] = relu(pooled[b] @ W1 + b1) @ W2 + b2  ; grid 64 x 128, all f32
__global__ __launch_bounds__(128) void k_mlp(const float* __restrict__ pooled,
                                             const float* __restrict__ W1,
                                             const float* __restrict__ b1,
                                             const float* __restrict__ W2,
                                             const float* __restrict__ b2,
                                             float* __restrict__ out) {
    __shared__ float p[128], t1[128];
    int b = blockIdx.x, t = threadIdx.x;
    p[t] = pooled[b * CH + t];
    __syncthreads();
    float acc = b1[t];
    for (int k = 0; k < 128; ++k) acc += p[k] * W1[k * 128 + t];
    t1[t] = fmaxf(acc, 0.f);
    __syncthreads();
    if (t < 64) {
        float o = b2[t];
        for (int k = 0; k < 128; ++k) o += t1[k] * W2[k * 64 + t];
        out[b * 64 + t] = o;
    }
}

// ---------------------------------------------------------------------------
extern "C" void kernel_launch(void* const* d_in, const int* in_sizes, int n_in,
                              void* d_out, int out_size, void* d_ws, size_t ws_size,
                              hipStream_t stream) {
    const float* x_in   = (const float*)d_in[0];
    const int*   ei     = (const int*)d_in[1];
    const int*   batch  = (const int*)d_in[2];
    const float* convW1 = (const float*)d_in[3];
    const float* convb1 = (const float*)d_in[4];
    const float* bn_g   = (const float*)d_in[5];
    const float* bn_b   = (const float*)d_in[6];
    const float* convW2 = (const float*)d_in[7];
    const float* convb2 = (const float*)d_in[8];
    const float* recW1  = (const float*)d_in[9];
    const float* recb1  = (const float*)d_in[10];
    const float* recW2  = (const float*)d_in[11];
    const float* recb2  = (const float*)d_in[12];
    const float* recW3  = (const float*)d_in[13];
    const float* recb3  = (const float*)d_in[14];
    const float* mlpW1  = (const float*)d_in[15];
    const float* mlpb1  = (const float*)d_in[16];
    const float* mlpW2  = (const float*)d_in[17];
    const float* mlpb2  = (const float*)d_in[18];

    float* out   = (float*)d_out;      // [64*64] out, then [50000*4] x_rec
    float* x_rec = out + 4096;

    char* w = (char*)d_ws;
    u16*   x16    = (u16*)w;    w += (size_t)NN * CH * 2;      // bf16 copy of x_in
    u16*   h16    = (u16*)w;    w += (size_t)NN * CH * 2;      // GEMM1 out (bf16)
    u16*   xc     = (u16*)w;    w += (size_t)NN * CH * 2;      // layer output
    u16*   Wt     = (u16*)w;    w += (size_t)9 * 16384 * 2;    // transposed bf16 weights
    float* gstats = (float*)w;  w += (size_t)3 * 256 * 4;      // BN sums per layer
    float* scale  = (float*)w;  w += 128 * 4;
    float* shift  = (float*)w;  w += 128 * 4;
    float* pooled = (float*)w;  w += (size_t)BB * CH * 4;
    int*   deg    = (int*)w;    w += (size_t)NN * 4;
    int*   bsum   = (int*)w;    w += (size_t)NSB * 4;
    int*   rowptr = (int*)w;    w += (size_t)(NN + 1) * 4;
    int*   cur    = (int*)w;    w += (size_t)NN * 4;
    int*   perm   = (int*)w;    w += (size_t)EE * 4;

    dim3 b256(256), b128(128);

    // CSR build + weight transpose + x->bf16 + zeroing
    k_zero2<<<231, b256, 0, stream>>>(deg, pooled, gstats);
    k_count<<<2344, b256, 0, stream>>>(ei, deg);
    k_scanA<<<NSB, b256, 0, stream>>>(deg, bsum);
    k_scanB<<<NSB, b256, 0, stream>>>(deg, bsum, rowptr, cur);
    k_fill<<<2344, b256, 0, stream>>>(ei, cur, perm);
    k_cvt<<<3125, b256, 0, stream>>>(x_in, x16);
    k_transpose_all<<<576, b256, 0, stream>>>(convW1, convW2, recW1, recW2, recW3, Wt);

    const u16* cur_x = x16;
    for (int l = 0; l < LL; ++l) {
        // fused gather + GEMM1 + stats
        k_g1<<<NGB, b256, 0, stream>>>(cur_x, rowptr, perm, Wt + l * 16384,
                                       convb1 + l * 128, h16, gstats + l * 256);
        k_bnparam<<<1, b128, 0, stream>>>(gstats + l * 256, bn_g + l * 128,
                                          bn_b + l * 128, scale, shift);
        if (l < LL - 1)
            k_g2<<<NGB, b256, 0, stream>>>(h16, Wt + (3 + l) * 16384,
                                           convb2 + l * 128, scale, shift, xc);
        else
            k_tail<<<NGB, b256, 0, stream>>>(h16, Wt, convb2 + 2 * 128, scale, shift,
                                             recb1, recb2, recb3, xc, x_rec);
        cur_x = xc;
    }
    // pooling + final MLP
    k_pool<<<NPB, b256, 0, stream>>>(xc, batch, pooled);
    k_mlp<<<64, b128, 0, stream>>>(pooled, mlpW1, mlpb1, mlpW2, mlpb2, out);
}

// Round 14
// 433.072 us; speedup vs baseline: 1.1706x; 1.1706x over previous
//
#include <hip/hip_runtime.h>

#define NN 50000
#define EE 600000
#define BB 64
#define CH 128
#define LL 3
#define NGB 782   // 64-row tiles: ceil(50000/64) -> ~3 blocks/CU for TLP
#define NSB 196   // scan blocks = ceil(50000/256)
#define NPB 392   // pool blocks = ceil(50000/128)

typedef unsigned short u16;
typedef unsigned int u32;
typedef short s16x8 __attribute__((ext_vector_type(8)));
typedef float f32x4 __attribute__((ext_vector_type(4)));

__device__ __forceinline__ u16 f2b(float f) {
    u32 x = __float_as_uint(f);
    return (u16)((x + 0x7FFFu + ((x >> 16) & 1u)) >> 16);  // RNE f32->bf16
}
__device__ __forceinline__ float b2f(u16 u) {
    return __uint_as_float(((u32)u) << 16);
}

// ---------------------------------------------------------------------------
// zero: deg[NN], pooled[BB*CH], gstats[3*256]
// ---------------------------------------------------------------------------
__global__ __launch_bounds__(256) void k_zero2(int* __restrict__ deg,
                                               float* __restrict__ pooled,
                                               float* __restrict__ gstats) {
    int i = blockIdx.x * 256 + threadIdx.x;
    if (i < NN) deg[i] = 0;
    int j = i - NN;
    if (j >= 0 && j < BB * CH) pooled[j] = 0.f;
    int k = j - BB * CH;
    if (k >= 0 && k < 3 * 256) gstats[k] = 0.f;
}

__global__ __launch_bounds__(256) void k_count(const int* __restrict__ ei,
                                               int* __restrict__ deg) {
    int e = blockIdx.x * 256 + threadIdx.x;
    if (e < EE) atomicAdd(&deg[ei[EE + e]], 1);
}

// stage A: per-block (256 elems) sum of deg -> bsum[blk]
__global__ __launch_bounds__(256) void k_scanA(const int* __restrict__ deg,
                                               int* __restrict__ bsum) {
    __shared__ int sm[256];
    int i = blockIdx.x * 256 + threadIdx.x;
    sm[threadIdx.x] = (i < NN) ? deg[i] : 0;
    __syncthreads();
    for (int off = 128; off > 0; off >>= 1) {
        if (threadIdx.x < off) sm[threadIdx.x] += sm[threadIdx.x + off];
        __syncthreads();
    }
    if (threadIdx.x == 0) bsum[blockIdx.x] = sm[0];
}

// stage B: scan bsum in LDS -> block offset; local scan -> rowptr & cur
__global__ __launch_bounds__(256) void k_scanB(const int* __restrict__ deg,
                                               const int* __restrict__ bsum,
                                               int* __restrict__ rowptr,
                                               int* __restrict__ cur) {
    __shared__ int sb[256], sd[256];
    int t = threadIdx.x;
    sb[t] = (t < NSB) ? bsum[t] : 0;
    __syncthreads();
    for (int off = 1; off < 256; off <<= 1) {
        int v = (t >= off) ? sb[t - off] : 0;
        __syncthreads();
        sb[t] += v;
        __syncthreads();
    }
    int blockOff = (blockIdx.x == 0) ? 0 : sb[blockIdx.x - 1];
    int i = blockIdx.x * 256 + t;
    int d = (i < NN) ? deg[i] : 0;
    sd[t] = d;
    __syncthreads();
    for (int off = 1; off < 256; off <<= 1) {
        int v = (t >= off) ? sd[t - off] : 0;
        __syncthreads();
        sd[t] += v;
        __syncthreads();
    }
    int excl = blockOff + sd[t] - d;
    if (i < NN) { rowptr[i] = excl; cur[i] = excl; }
    if (i == NN - 1) rowptr[NN] = excl + d;
}

__global__ __launch_bounds__(256) void k_fill(const int* __restrict__ ei,
                                              int* __restrict__ cur,
                                              int* __restrict__ perm) {
    int e = blockIdx.x * 256 + threadIdx.x;
    if (e < EE) {
        int dst = ei[EE + e];
        int idx = atomicAdd(&cur[dst], 1);
        perm[idx] = ei[e];
    }
}

// x16 = bf16(x_in), 8 elements/thread. grid 3125 x 256.
__global__ __launch_bounds__(256) void k_cvt(const float* __restrict__ x,
                                             u16* __restrict__ y) {
    long base = (long)(blockIdx.x * 256 + threadIdx.x) * 8;
    if (base < (long)NN * CH) {
        float4 f0 = *(const float4*)(x + base);
        float4 f1 = *(const float4*)(x + base + 4);
        union { u16 pk[8]; uint4 v; } uu;
        uu.pk[0] = f2b(f0.x); uu.pk[1] = f2b(f0.y);
        uu.pk[2] = f2b(f0.z); uu.pk[3] = f2b(f0.w);
        uu.pk[4] = f2b(f1.x); uu.pk[5] = f2b(f1.y);
        uu.pk[6] = f2b(f1.z); uu.pk[7] = f2b(f1.w);
        *(uint4*)(y + base) = uu.v;
    }
}

// ---------------------------------------------------------------------------
// Gather (standalone, max occupancy: no LDS, ~40 VGPR):
// y[dst] = bf16( x[dst] + sum_src x[src] ); one dst per 16-lane group;
// 4-way unrolled edge loop -> 4 independent load chains per group.
// grid 3125 x 256 (16 dst/block).
// ---------------------------------------------------------------------------
__global__ __launch_bounds__(256) void k_gather(const u16* __restrict__ x,
                                                const int* __restrict__ rowptr,
                                                const int* __restrict__ perm,
                                                u16* __restrict__ y) {
    int dst = blockIdx.x * 16 + (threadIdx.x >> 4);
    if (dst >= NN) return;
    int lane = threadIdx.x & 15;
    int co = lane * 8;
    int beg = rowptr[dst], end = rowptr[dst + 1];
    union { u16 pk[8]; uint4 v; } uu;
    uu.v = *(const uint4*)(x + (long)dst * CH + co);
    float a[8], b[8], c[8], d[8];
#pragma unroll
    for (int j = 0; j < 8; ++j) { a[j] = b2f(uu.pk[j]); b[j] = 0.f; c[j] = 0.f; d[j] = 0.f; }
    int e = beg;
    for (; e + 3 < end; e += 4) {
        int s0 = perm[e], s1 = perm[e + 1], s2 = perm[e + 2], s3 = perm[e + 3];
        union { u16 pk[8]; uint4 v; } v0, v1, v2, v3;
        v0.v = *(const uint4*)(x + (long)s0 * CH + co);
        v1.v = *(const uint4*)(x + (long)s1 * CH + co);
        v2.v = *(const uint4*)(x + (long)s2 * CH + co);
        v3.v = *(const uint4*)(x + (long)s3 * CH + co);
#pragma unroll
        for (int j = 0; j < 8; ++j) {
            a[j] += b2f(v0.pk[j]); b[j] += b2f(v1.pk[j]);
            c[j] += b2f(v2.pk[j]); d[j] += b2f(v3.pk[j]);
        }
    }
    for (; e < end; ++e) {
        int s0 = perm[e];
        union { u16 pk[8]; uint4 v; } v0;
        v0.v = *(const uint4*)(x + (long)s0 * CH + co);
#pragma unroll
        for (int j = 0; j < 8; ++j) a[j] += b2f(v0.pk[j]);
    }
    union { u16 pk[8]; uint4 v; } ov;
#pragma unroll
    for (int j = 0; j < 8; ++j) ov.pk[j] = f2b((a[j] + b[j]) + (c[j] + d[j]));
    *(uint4*)(y + (long)dst * CH + co) = ov.v;
}

// ---------------------------------------------------------------------------
// Transpose + convert weights once: Wt[slot][n*128+k] = bf16(W[k][n])
// slots 0-2: convW1[l], 3-5: convW2[l], 6: recW1, 7: recW2, 8: recW3 (zero-pad)
// ---------------------------------------------------------------------------
__global__ __launch_bounds__(256) void k_transpose_all(
    const float* __restrict__ cW1, const float* __restrict__ cW2,
    const float* __restrict__ rW1, const float* __restrict__ rW2,
    const float* __restrict__ rW3, u16* __restrict__ Wt) {
    int idx = blockIdx.x * 256 + threadIdx.x;
    if (idx < 8 * 16384) {
        int slot = idx >> 14;
        int wi = idx & 16383;
        int k = wi >> 7, n = wi & 127;
        const float* src = slot < 3 ? cW1 + slot * 16384
                         : slot < 6 ? cW2 + (slot - 3) * 16384
                         : slot == 6 ? rW1 : rW2;
        Wt[slot * 16384 + n * 128 + k] = f2b(src[wi]);
    } else if (idx < 9 * 16384) {
        int j = idx - 8 * 16384;
        int n = j >> 7, k = j & 127;
        Wt[8 * 16384 + j] = (n < 4) ? f2b(rW3[k * 4 + n]) : (u16)0;
    }
}

// ---------------------------------------------------------------------------
// 64-row GEMM building blocks (layouts verified m89/m91/R13; XOR-swizzle).
// Block = 256 threads = 4 waves; wave wv owns rows wv*16..wv*16+15.
// LDS: sA 64x128 (16 KB) + sB 128x128 (32 KB) = 48 KB -> 3 blocks/CU.
// ---------------------------------------------------------------------------
__device__ __forceinline__ void stageB8(const u16* __restrict__ Wt, u16* sB,
                                        int s, int rr) {
#pragma unroll
    for (int it = 0; it < 8; ++it) {
        int n = it * 16 + rr;
        uint4 u = *(const uint4*)(Wt + n * CH + 8 * s);
        *(uint4*)(&sB[n * CH + ((s ^ (n & 15)) * 8)]) = u;
    }
}

// 8 column-tiles over full K for this wave's 16 rows.
__device__ __forceinline__ void mfma64(const u16* sA, const u16* sB,
                                       f32x4 acc[8], int wv, int quad, int l16) {
    f32x4 z = {0.f, 0.f, 0.f, 0.f};
#pragma unroll
    for (int t = 0; t < 8; ++t) acc[t] = z;
    const u16* pa = sA + (wv * 16 + l16) * CH;
#pragma unroll
    for (int kc = 0; kc < 4; ++kc) {
        int off = (((kc << 2) | quad) ^ l16) << 3;
        s16x8 a0 = *(const s16x8*)(pa + off);
#pragma unroll
        for (int t = 0; t < 8; ++t) {
            s16x8 bfr = *(const s16x8*)(sB + (t * 16 + l16) * CH + off);
            acc[t] = __builtin_amdgcn_mfma_f32_16x16x32_bf16(a0, bfr, acc[t], 0, 0, 0);
        }
    }
}

__device__ __forceinline__ void biasrelu64(f32x4 acc[8],
                                           const float* __restrict__ bias, int l16) {
#pragma unroll
    for (int t = 0; t < 8; ++t) {
        float bv = bias[t * 16 + l16];
#pragma unroll
        for (int r = 0; r < 4; ++r)
            acc[t][r] = fmaxf(acc[t][r] + bv, 0.f);
    }
}

// write C tile (in acc) back into sA as bf16 with the A-read XOR-swizzle.
__device__ __forceinline__ void restage64(const f32x4 acc[8], u16* sA,
                                          int wv, int quad, int l16) {
#pragma unroll
    for (int t = 0; t < 8; ++t) {
        int chunk = (t << 1) | (l16 >> 3);
        int o7 = l16 & 7;
#pragma unroll
        for (int r = 0; r < 4; ++r) {
            int lr = wv * 16 + quad * 4 + r;
            sA[lr * CH + ((chunk ^ (lr & 15)) << 3) + o7] = f2b(acc[t][r]);
        }
    }
}

// ---------------------------------------------------------------------------
// GEMM1 + stats: h16 = y16 @ W1 + b1 (pre-relu, bf16); block channel
// sum/sumsq atomically added to gstats[256]. 64-row tiles, 782 blocks.
// ---------------------------------------------------------------------------
__global__ __launch_bounds__(256, 3) void k_g1(
    const u16* __restrict__ y16, const u16* __restrict__ Wt1,
    const float* __restrict__ cb1, u16* __restrict__ h16,
    float* __restrict__ gstats) {
    __shared__ u16 sA[64 * CH];    // 16 KB
    __shared__ u16 sB[128 * CH];   // 32 KB
    const int tid = threadIdx.x;
    const int s = tid & 15, rr = tid >> 4;
    const int r0 = blockIdx.x * 64;
    const int lane = tid & 63, wv = tid >> 6, quad = lane >> 4, l16 = lane & 15;

    stageB8(Wt1, sB, s, rr);
#pragma unroll
    for (int it = 0; it < 4; ++it) {
        int lr = it * 16 + rr;
        int gr = r0 + lr;
        union { u16 pk[8]; uint4 v; } uu;
        if (gr < NN) {
            uu.v = *(const uint4*)(y16 + (long)gr * CH + 8 * s);
        } else {
#pragma unroll
            for (int j = 0; j < 8; ++j) uu.pk[j] = 0;
        }
        *(uint4*)(&sA[lr * CH + ((s ^ (lr & 15)) * 8)]) = uu.v;
    }
    __syncthreads();

    f32x4 acc[8];
    mfma64(sA, sB, acc, wv, quad, l16);

    // bias add (keep pre-relu h), stats over valid rows, write h16
    float ss[8], qq[8];
#pragma unroll
    for (int t = 0; t < 8; ++t) {
        float bv = cb1[t * 16 + l16];
        int col = t * 16 + l16;
        ss[t] = 0.f; qq[t] = 0.f;
        int rbase = r0 + wv * 16 + quad * 4;
#pragma unroll
        for (int r = 0; r < 4; ++r) {
            float v = acc[t][r] + bv;
            int row = rbase + r;
            if (row < NN) {
                ss[t] += v; qq[t] += v * v;
                h16[(long)row * CH + col] = f2b(v);
            }
        }
    }
#pragma unroll
    for (int t = 0; t < 8; ++t) {
        ss[t] += __shfl_xor(ss[t], 16);
        ss[t] += __shfl_xor(ss[t], 32);
        qq[t] += __shfl_xor(qq[t], 16);
        qq[t] += __shfl_xor(qq[t], 32);
    }
    float* red = (float*)sA;   // sA dead after mfma
    __syncthreads();
    if (lane < 16) {
#pragma unroll
        for (int t = 0; t < 8; ++t) {
            red[wv * 256 + t * 16 + l16] = ss[t];
            red[wv * 256 + 128 + t * 16 + l16] = qq[t];
        }
    }
    __syncthreads();
    unsafeAtomicAdd(&gstats[tid],
                    red[tid] + red[256 + tid] + red[512 + tid] + red[768 + tid]);
}

// BN params from gstats. 1 block x 128.
__global__ __launch_bounds__(128) void k_bnparam(const float* __restrict__ gstats,
                                                 const float* __restrict__ g,
                                                 const float* __restrict__ b,
                                                 float* __restrict__ scale,
                                                 float* __restrict__ shift) {
    int t = threadIdx.x;
    float mu = gstats[t] / (float)NN;
    float var = gstats[128 + t] / (float)NN - mu * mu;
    float rstd = rsqrtf(var + 1e-5f);
    float sc = g[t] * rstd;
    scale[t] = sc;
    shift[t] = b[t] - mu * sc;
}

// ---------------------------------------------------------------------------
// GEMM2 (layers 0,1): xc = relu(relu(BN(h16)) @ W2 + b2), BN fused in staging.
// ---------------------------------------------------------------------------
__global__ __launch_bounds__(256, 3) void k_g2(
    const u16* __restrict__ h16, const u16* __restrict__ Wt2,
    const float* __restrict__ cb2, const float* __restrict__ scale,
    const float* __restrict__ shift, u16* __restrict__ xc) {
    __shared__ u16 sA[64 * CH];
    __shared__ u16 sB[128 * CH];
    const int tid = threadIdx.x;
    const int s = tid & 15, rr = tid >> 4;
    const int r0 = blockIdx.x * 64;
    const int lane = tid & 63, wv = tid >> 6, quad = lane >> 4, l16 = lane & 15;

    float sc[8], sh[8];
#pragma unroll
    for (int j = 0; j < 8; ++j) { sc[j] = scale[8 * s + j]; sh[j] = shift[8 * s + j]; }

    stageB8(Wt2, sB, s, rr);
#pragma unroll
    for (int it = 0; it < 4; ++it) {
        int lr = it * 16 + rr;
        int gr = r0 + lr;
        union { u16 pk[8]; uint4 v; } uu;
        if (gr < NN) {
            uu.v = *(const uint4*)(h16 + (long)gr * CH + 8 * s);
#pragma unroll
            for (int j = 0; j < 8; ++j)
                uu.pk[j] = f2b(fmaxf(b2f(uu.pk[j]) * sc[j] + sh[j], 0.f));
        } else {
#pragma unroll
            for (int j = 0; j < 8; ++j) uu.pk[j] = 0;
        }
        *(uint4*)(&sA[lr * CH + ((s ^ (lr & 15)) * 8)]) = uu.v;
    }
    __syncthreads();

    f32x4 acc[8];
    mfma64(sA, sB, acc, wv, quad, l16);
    biasrelu64(acc, cb2, l16);
#pragma unroll
    for (int t = 0; t < 8; ++t) {
        int col = t * 16 + l16;
        int rbase = r0 + wv * 16 + quad * 4;
#pragma unroll
        for (int r = 0; r < 4; ++r) {
            int row = rbase + r;
            if (row < NN) xc[(long)row * CH + col] = f2b(acc[t][r]);
        }
    }
}

// ---------------------------------------------------------------------------
// Last-layer tail: GEMM2(l=2) + rec1 + rec2 + rec3, tile-resident (R13-verified)
// ---------------------------------------------------------------------------
__global__ __launch_bounds__(256, 3) void k_tail(
    const u16* __restrict__ h16, const u16* __restrict__ Wt,
    const float* __restrict__ cb2, const float* __restrict__ scale,
    const float* __restrict__ shift, const float* __restrict__ rb1,
    const float* __restrict__ rb2, const float* __restrict__ rb3,
    u16* __restrict__ xc, float* __restrict__ x_rec) {
    __shared__ u16 sA[64 * CH];
    __shared__ u16 sB[128 * CH];
    const int tid = threadIdx.x;
    const int s = tid & 15, rr = tid >> 4;
    const int r0 = blockIdx.x * 64;
    const int lane = tid & 63, wv = tid >> 6, quad = lane >> 4, l16 = lane & 15;

    float sc[8], sh[8];
#pragma unroll
    for (int j = 0; j < 8; ++j) { sc[j] = scale[8 * s + j]; sh[j] = shift[8 * s + j]; }

    // ---- GEMM2 (layer 2) ----
    stageB8(Wt + 5 * 16384, sB, s, rr);
#pragma unroll
    for (int it = 0; it < 4; ++it) {
        int lr = it * 16 + rr;
        int gr = r0 + lr;
        union { u16 pk[8]; uint4 v; } uu;
        if (gr < NN) {
            uu.v = *(const uint4*)(h16 + (long)gr * CH + 8 * s);
#pragma unroll
            for (int j = 0; j < 8; ++j)
                uu.pk[j] = f2b(fmaxf(b2f(uu.pk[j]) * sc[j] + sh[j], 0.f));
        } else {
#pragma unroll
            for (int j = 0; j < 8; ++j) uu.pk[j] = 0;
        }
        *(uint4*)(&sA[lr * CH + ((s ^ (lr & 15)) * 8)]) = uu.v;
    }
    __syncthreads();

    f32x4 acc[8];
    mfma64(sA, sB, acc, wv, quad, l16);
    biasrelu64(acc, cb2, l16);
#pragma unroll
    for (int t = 0; t < 8; ++t) {
        int col = t * 16 + l16;
        int rbase = r0 + wv * 16 + quad * 4;
#pragma unroll
        for (int r = 0; r < 4; ++r) {
            int row = rbase + r;
            if (row < NN) xc[(long)row * CH + col] = f2b(acc[t][r]);
        }
    }
    // ---- rec1 ----
    __syncthreads();
    restage64(acc, sA, wv, quad, l16);
    stageB8(Wt + 6 * 16384, sB, s, rr);
    __syncthreads();
    mfma64(sA, sB, acc, wv, quad, l16);
    biasrelu64(acc, rb1, l16);
    // ---- rec2 ----
    __syncthreads();
    restage64(acc, sA, wv, quad, l16);
    stageB8(Wt + 7 * 16384, sB, s, rr);
    __syncthreads();
    mfma64(sA, sB, acc, wv, quad, l16);
    biasrelu64(acc, rb2, l16);
    // ---- rec3 (N=4, single 16-col tile) ----
    __syncthreads();
    restage64(acc, sA, wv, quad, l16);
    {
        int n = rr;  // 16 B-rows
        uint4 u = *(const uint4*)(Wt + 8 * 16384 + n * CH + 8 * s);
        *(uint4*)(&sB[n * CH + ((s ^ (n & 15)) * 8)]) = u;
    }
    __syncthreads();
    f32x4 a4 = {0.f, 0.f, 0.f, 0.f};
    const u16* pa = sA + (wv * 16 + l16) * CH;
#pragma unroll
    for (int kc = 0; kc < 4; ++kc) {
        int off = (((kc << 2) | quad) ^ l16) << 3;
        s16x8 a0 = *(const s16x8*)(pa + off);
        s16x8 bfr = *(const s16x8*)(sB + l16 * CH + off);
        a4 = __builtin_amdgcn_mfma_f32_16x16x32_bf16(a0, bfr, a4, 0, 0, 0);
    }
    if (l16 < 4) {
        float bv = rb3[l16];
        int rbase = r0 + wv * 16 + quad * 4;
#pragma unroll
        for (int r = 0; r < 4; ++r) {
            int row = rbase + r;
            if (row < NN) x_rec[(long)row * 4 + l16] = fmaxf(a4[r] + bv, 0.f);
        }
    }
}

// ---------------------------------------------------------------------------
// global_add_pool, parallel: 392 blocks x 128 rows; run-length accumulate.
// ---------------------------------------------------------------------------
__global__ __launch_bounds__(256) void k_pool(const u16* __restrict__ x,
                                              const int* __restrict__ batch,
                                              float* __restrict__ pooled) {
    int r0 = blockIdx.x * 128;
    if (r0 >= NN) return;
    int rend = r0 + 128 < NN ? r0 + 128 : NN;
    int c = threadIdx.x & 127;
    int half = threadIdx.x >> 7;
    int r = r0 + half;
    if (r >= rend) return;
    int g = batch[r];
    float s = 0.f;
    for (; r < rend; r += 2) {
        int gg = batch[r];
        if (gg != g) {
            unsafeAtomicAdd(pooled + g * CH + c, s);
            s = 0.f;
            g = gg;
        }
        s += b2f(x[(long)r * CH + c]);
    }
    unsafeAtomicAdd(pooled + g * CH + c, s);
}

// out[b] = relu(pooled[b] @ W1 + b1) @ W2 + b2  ; grid 64 x 128, all f32
__global__ __launch_bounds__(128) void k_mlp(const float* __restrict__ pooled,
                                             const float* __restrict__ W1,
                                             const float* __restrict__ b1,
                                             const float* __restrict__ W2,
                                             const float* __restrict__ b2,
                                             float* __restrict__ out) {
    __shared__ float p[128], t1[128];
    int b = blockIdx.x, t = threadIdx.x;
    p[t] = pooled[b * CH + t];
    __syncthreads();
    float acc = b1[t];
    for (int k = 0; k < 128; ++k) acc += p[k] * W1[k * 128 + t];
    t1[t] = fmaxf(acc, 0.f);
    __syncthreads();
    if (t < 64) {
        float o = b2[t];
        for (int k = 0; k < 128; ++k) o += t1[k] * W2[k * 64 + t];
        out[b * 64 + t] = o;
    }
}

// ---------------------------------------------------------------------------
extern "C" void kernel_launch(void* const* d_in, const int* in_sizes, int n_in,
                              void* d_out, int out_size, void* d_ws, size_t ws_size,
                              hipStream_t stream) {
    const float* x_in   = (const float*)d_in[0];
    const int*   ei     = (const int*)d_in[1];
    const int*   batch  = (const int*)d_in[2];
    const float* convW1 = (const float*)d_in[3];
    const float* convb1 = (const float*)d_in[4];
    const float* bn_g   = (const float*)d_in[5];
    const float* bn_b   = (const float*)d_in[6];
    const float* convW2 = (const float*)d_in[7];
    const float* convb2 = (const float*)d_in[8];
    const float* recW1  = (const float*)d_in[9];
    const float* recb1  = (const float*)d_in[10];
    const float* recW2  = (const float*)d_in[11];
    const float* recb2  = (const float*)d_in[12];
    const float* recW3  = (const float*)d_in[13];
    const float* recb3  = (const float*)d_in[14];
    const float* mlpW1  = (const float*)d_in[15];
    const float* mlpb1  = (const float*)d_in[16];
    const float* mlpW2  = (const float*)d_in[17];
    const float* mlpb2  = (const float*)d_in[18];

    float* out   = (float*)d_out;      // [64*64] out, then [50000*4] x_rec
    float* x_rec = out + 4096;

    char* w = (char*)d_ws;
    u16*   x16    = (u16*)w;    w += (size_t)NN * CH * 2;      // bf16 copy of x_in
    u16*   y16    = (u16*)w;    w += (size_t)NN * CH * 2;      // gather output
    u16*   h16    = (u16*)w;    w += (size_t)NN * CH * 2;      // GEMM1 out (bf16)
    u16*   xc     = (u16*)w;    w += (size_t)NN * CH * 2;      // layer output
    u16*   Wt     = (u16*)w;    w += (size_t)9 * 16384 * 2;    // transposed bf16 weights
    float* gstats = (float*)w;  w += (size_t)3 * 256 * 4;      // BN sums per layer
    float* scale  = (float*)w;  w += 128 * 4;
    float* shift  = (float*)w;  w += 128 * 4;
    float* pooled = (float*)w;  w += (size_t)BB * CH * 4;
    int*   deg    = (int*)w;    w += (size_t)NN * 4;
    int*   bsum   = (int*)w;    w += (size_t)NSB * 4;
    int*   rowptr = (int*)w;    w += (size_t)(NN + 1) * 4;
    int*   cur    = (int*)w;    w += (size_t)NN * 4;
    int*   perm   = (int*)w;    w += (size_t)EE * 4;

    dim3 b256(256), b128(128);

    // CSR build + weight transpose + x->bf16 + zeroing
    k_zero2<<<231, b256, 0, stream>>>(deg, pooled, gstats);
    k_count<<<2344, b256, 0, stream>>>(ei, deg);
    k_scanA<<<NSB, b256, 0, stream>>>(deg, bsum);
    k_scanB<<<NSB, b256, 0, stream>>>(deg, bsum, rowptr, cur);
    k_fill<<<2344, b256, 0, stream>>>(ei, cur, perm);
    k_cvt<<<3125, b256, 0, stream>>>(x_in, x16);
    k_transpose_all<<<576, b256, 0, stream>>>(convW1, convW2, recW1, recW2, recW3, Wt);

    const u16* cur_x = x16;
    for (int l = 0; l < LL; ++l) {
        k_gather<<<3125, b256, 0, stream>>>(cur_x, rowptr, perm, y16);
        k_g1<<<NGB, b256, 0, stream>>>(y16, Wt + l * 16384, convb1 + l * 128,
                                       h16, gstats + l * 256);
        k_bnparam<<<1, b128, 0, stream>>>(gstats + l * 256, bn_g + l * 128,
                                          bn_b + l * 128, scale, shift);
        if (l < LL - 1)
            k_g2<<<NGB, b256, 0, stream>>>(h16, Wt + (3 + l) * 16384,
                                           convb2 + l * 128, scale, shift, xc);
        else
            k_tail<<<NGB, b256, 0, stream>>>(h16, Wt, convb2 + 2 * 128, scale, shift,
                                             recb1, recb2, recb3, xc, x_rec);
        cur_x = xc;
    }
    // pooling + final MLP
    k_pool<<<NPB, b256, 0, stream>>>(xc, batch, pooled);
    k_mlp<<<64, b128, 0, stream>>>(pooled, mlpW1, mlpb1, mlpW2, mlpb2, out);
}